// Round 6
// baseline (378.928 us; speedup 1.0000x reference)
//
#include <hip/hip_runtime.h>
#include <math.h>

#define BB 32
#define NN 128
#define DD 64
#define EE 5
#define TT 6          // 1+T iterations
#define NE (NN*EE)    // 640
#define MSG_SZ ((size_t)BB*NN*EE*DD)   // 1310720
#define COL_SZ ((size_t)BB*NN*EE)      // 20480
#define PROP_SZ ((size_t)BB*NN*DD)     // 262144

__device__ __forceinline__ float fsig(float x) {
    float t = __expf(-x);
    return __fdividef(1.f, 1.f + t);
}
__device__ __forceinline__ float ftanh_(float x) {
    float xc = fminf(fmaxf(x, -15.f), 15.f);
    float t = __expf(-2.f * xc);
    return 1.f - __fdividef(2.f * t, 1.f + t);
}

// ===================== per-iteration kernel =====================
// k_iter<DO_B,DO_A>: PhaseB(t) (scores->out, merged, GRU) then PhaseA(t+1)
// (msg/rowv/colv for own rows from the freshly updated LDS prop).
// Block owns 4 (b,i) rows; block = 256 (4 waves); grid = B*N/4 = 1024.
// Cross-block msg visibility is provided by the kernel-launch boundary.
template<int DO_B, int DO_A>
__global__ void __launch_bounds__(256) k_iter(
    const float* __restrict__ propR, float* __restrict__ propW,
    const float* __restrict__ msgR, float* __restrict__ msgW,
    const float* __restrict__ colvR, float* __restrict__ colvW,
    const float* __restrict__ rowvR, float* __restrict__ rowvW,
    const int* __restrict__ mask,
    const float* __restrict__ We, const float* __restrict__ be,
    const float* __restrict__ Wa, const float* __restrict__ ba,
    const float* __restrict__ Wr, const float* __restrict__ br,
    const float* __restrict__ Wz, const float* __restrict__ bz,
    const float* __restrict__ Wh, const float* __restrict__ bh,
    float* __restrict__ out_t)
{
    const int bi0 = blockIdx.x * 4;
    const int b = bi0 >> 7;
    const int tid = threadIdx.x;
    const int g = tid >> 6;        // wave 0..3
    const int f = tid & 63;        // lane
    const int d = f;

    __shared__ float s_pt[DD][4];         // prop transposed [d][q]
    __shared__ float s_mt[DD][4];         // merged transposed
    __shared__ float s_rpt[DD][4];        // r*prop
    __shared__ float s_sc[NE][4];         // scores [je][q]
    __shared__ float s_part[4][4][DD];
    __shared__ float s_part2[4][4][DD];
    __shared__ float s_rv[4][EE];         // row logits for own 4 rows

    s_pt[d][g] = propR[(bi0 + g) * DD + d];
    if (DO_B && tid < 4 * EE) s_rv[tid / EE][tid % EE] = rowvR[bi0 * EE + tid];
    __syncthreads();

    if (DO_B) {
        // ---- scores -> out + LDS ----
        for (int je = tid; je < NE; je += 256) {
            const int j = je / EE, e = je - j * EE;
            const float cv = colvR[b * NE + je] + ba[e];
            #pragma unroll
            for (int qq = 0; qq < 4; ++qq) {
                float lg = s_rv[qq][e] + cv;
                float m = (float)mask[((size_t)(b * NN) + (bi0 & (NN-1)) + qq) * NN + j];
                float sc = fsig(lg) * m;
                s_sc[je][qq] = sc;
                out_t[(size_t)(bi0 + qq) * NE + je] = sc;
            }
        }
        __syncthreads();

        // ---- merged partials: wave g covers je in [g*160, g*160+160) ----
        {
            const float* mb = msgR + (size_t)b * NE * DD;
            float a0=0.f, a1=0.f, a2=0.f, a3=0.f;
            const int je0 = g * 160;
            #pragma unroll 4
            for (int je = je0; je < je0 + 160; ++je) {
                float m = mb[(size_t)je * DD + d];
                float4 sc = *(const float4*)&s_sc[je][0];
                a0 = fmaf(sc.x, m, a0); a1 = fmaf(sc.y, m, a1);
                a2 = fmaf(sc.z, m, a2); a3 = fmaf(sc.w, m, a3);
            }
            s_part[g][0][d]=a0; s_part[g][1][d]=a1;
            s_part[g][2][d]=a2; s_part[g][3][d]=a3;
        }
        __syncthreads();

        const float p_reg = s_pt[d][g];
        {
            float m_reg = s_part[0][g][d] + s_part[1][g][d]
                        + s_part[2][g][d] + s_part[3][g][d];
            s_mt[d][g] = m_reg;
        }
        __syncthreads();

        // ---- gates r,z: wave g covers a k-quarter; weights read once/block ----
        {
            const float* vsrc = (g & 2) ? &s_pt[0][0] : &s_mt[0][0];
            const int kbase = (g & 2) ? 64 : 0;
            const int k0 = (g & 1) * 32;
            float r0=0,r1=0,r2=0,r3=0, z0=0,z1=0,z2=0,z3=0;
            #pragma unroll 8
            for (int kk = 0; kk < 32; ++kk) {
                int k = k0 + kk;
                int kg = kbase + k;
                float wr = Wr[kg * DD + d];
                float wz = Wz[kg * DD + d];
                float4 v = *(const float4*)&vsrc[k * 4];
                r0=fmaf(v.x,wr,r0); r1=fmaf(v.y,wr,r1); r2=fmaf(v.z,wr,r2); r3=fmaf(v.w,wr,r3);
                z0=fmaf(v.x,wz,z0); z1=fmaf(v.y,wz,z1); z2=fmaf(v.z,wz,z2); z3=fmaf(v.w,wz,z3);
            }
            s_part[g][0][d]=r0; s_part[g][1][d]=r1; s_part[g][2][d]=r2; s_part[g][3][d]=r3;
            s_part2[g][0][d]=z0; s_part2[g][1][d]=z1; s_part2[g][2][d]=z2; s_part2[g][3][d]=z3;
        }
        __syncthreads();

        float z_reg;
        {
            float ar = br[d] + s_part[0][g][d] + s_part[1][g][d] + s_part[2][g][d] + s_part[3][g][d];
            float az = bz[d] + s_part2[0][g][d] + s_part2[1][g][d] + s_part2[2][g][d] + s_part2[3][g][d];
            float r = fsig(ar);
            z_reg = fsig(az);
            s_rpt[d][g] = r * p_reg;
        }
        __syncthreads();

        // ---- gate h: same k-split over [merged | r*prop] ----
        {
            const float* vsrc = (g & 2) ? &s_rpt[0][0] : &s_mt[0][0];
            const int kbase = (g & 2) ? 64 : 0;
            const int k0 = (g & 1) * 32;
            float h0=0,h1=0,h2=0,h3=0;
            #pragma unroll 8
            for (int kk = 0; kk < 32; ++kk) {
                int k = k0 + kk;
                int kg = kbase + k;
                float wh = Wh[kg * DD + d];
                float4 v = *(const float4*)&vsrc[k * 4];
                h0=fmaf(v.x,wh,h0); h1=fmaf(v.y,wh,h1); h2=fmaf(v.z,wh,h2); h3=fmaf(v.w,wh,h3);
            }
            s_part[g][0][d]=h0; s_part[g][1][d]=h1; s_part[g][2][d]=h2; s_part[g][3][d]=h3;
        }
        __syncthreads();

        {
            float ah = bh[d] + s_part[0][g][d] + s_part[1][g][d] + s_part[2][g][d] + s_part[3][g][d];
            float hh = ftanh_(ah);
            float pn = (1.f - z_reg) * p_reg + z_reg * hh;
            s_pt[d][g] = pn;                       // for PhaseA below
            propW[(bi0 + g) * DD + d] = pn;        // for next launch's PhaseB
        }
        __syncthreads();
    }

    if (DO_A) {
        // ---- msg(t+1)/rowv/colv for own 4 rows; experts e = g (+4 on wave 0) ----
        for (int e = g; e < EE; e += 4) {
            const float* w = We + e * DD * DD + f;
            const float bias = be[e * DD + f];
            float a0 = bias, a1 = bias, a2 = bias, a3 = bias;
            #pragma unroll 8
            for (int k = 0; k < DD; ++k) {
                float wv = w[k * DD];
                float4 p = *(const float4*)&s_pt[k][0];
                a0 = fmaf(p.x, wv, a0); a1 = fmaf(p.y, wv, a1);
                a2 = fmaf(p.z, wv, a2); a3 = fmaf(p.w, wv, a3);
            }
            msgW[((size_t)(bi0+0)*EE + e)*DD + f] = a0;
            msgW[((size_t)(bi0+1)*EE + e)*DD + f] = a1;
            msgW[((size_t)(bi0+2)*EE + e)*DD + f] = a2;
            msgW[((size_t)(bi0+3)*EE + e)*DD + f] = a3;

            const float war = Wa[e*2*DD + f], wac = Wa[e*2*DD + DD + f];
            float r0=a0*war, r1=a1*war, r2=a2*war, r3=a3*war;
            float c0=a0*wac, c1=a1*wac, c2=a2*wac, c3=a3*wac;
            #pragma unroll
            for (int off = 32; off; off >>= 1) {
                r0 += __shfl_xor(r0,off); r1 += __shfl_xor(r1,off);
                r2 += __shfl_xor(r2,off); r3 += __shfl_xor(r3,off);
                c0 += __shfl_xor(c0,off); c1 += __shfl_xor(c1,off);
                c2 += __shfl_xor(c2,off); c3 += __shfl_xor(c3,off);
            }
            if (f == 0) {
                rowvW[(bi0+0)*EE+e]=r0; rowvW[(bi0+1)*EE+e]=r1;
                rowvW[(bi0+2)*EE+e]=r2; rowvW[(bi0+3)*EE+e]=r3;
                colvW[(bi0+0)*EE+e]=c0; colvW[(bi0+1)*EE+e]=c1;
                colvW[(bi0+2)*EE+e]=c2; colvW[(bi0+3)*EE+e]=c3;
            }
        }
    }
}

// ===================== fallback path (round-2 proven, ~6.5 MB ws) =====================
__global__ void __launch_bounds__(320) k_msg(
    const float* __restrict__ prop, const float* __restrict__ We,
    const float* __restrict__ be, const float* __restrict__ Wa,
    float* __restrict__ msg, float* __restrict__ rowv, float* __restrict__ colv)
{
    const int bn0 = blockIdx.x * 4;
    const int tid = threadIdx.x;
    const int e = tid >> 6, f = tid & 63;
    __shared__ float s_pt[DD][4];
    if (tid < 256) {
        int q = tid >> 6, dd = tid & 63;
        s_pt[dd][q] = prop[(bn0 + q) * DD + dd];
    }
    __syncthreads();

    const float* w = We + e * DD * DD + f;
    const float bias = be[e * DD + f];
    float a0 = bias, a1 = bias, a2 = bias, a3 = bias;
    #pragma unroll 8
    for (int k = 0; k < DD; ++k) {
        float wv = w[k * DD];
        float4 p = *(const float4*)&s_pt[k][0];
        a0 = fmaf(p.x, wv, a0); a1 = fmaf(p.y, wv, a1);
        a2 = fmaf(p.z, wv, a2); a3 = fmaf(p.w, wv, a3);
    }
    msg[((size_t)(bn0+0)*EE + e)*DD + f] = a0;
    msg[((size_t)(bn0+1)*EE + e)*DD + f] = a1;
    msg[((size_t)(bn0+2)*EE + e)*DD + f] = a2;
    msg[((size_t)(bn0+3)*EE + e)*DD + f] = a3;

    const float war = Wa[e*2*DD + f], wac = Wa[e*2*DD + DD + f];
    float r0=a0*war, r1=a1*war, r2=a2*war, r3=a3*war;
    float c0=a0*wac, c1=a1*wac, c2=a2*wac, c3=a3*wac;
    #pragma unroll
    for (int off = 32; off; off >>= 1) {
        r0 += __shfl_xor(r0,off); r1 += __shfl_xor(r1,off);
        r2 += __shfl_xor(r2,off); r3 += __shfl_xor(r3,off);
        c0 += __shfl_xor(c0,off); c1 += __shfl_xor(c1,off);
        c2 += __shfl_xor(c2,off); c3 += __shfl_xor(c3,off);
    }
    if (f == 0) {
        rowv[(bn0+0)*EE+e]=r0; rowv[(bn0+1)*EE+e]=r1;
        rowv[(bn0+2)*EE+e]=r2; rowv[(bn0+3)*EE+e]=r3;
        colv[(bn0+0)*EE+e]=c0; colv[(bn0+1)*EE+e]=c1;
        colv[(bn0+2)*EE+e]=c2; colv[(bn0+3)*EE+e]=c3;
    }
}

extern "C" void kernel_launch(void* const* d_in, const int* in_sizes, int n_in,
                              void* d_out, int out_size, void* d_ws, size_t ws_size,
                              hipStream_t stream)
{
    const float* inputs = (const float*)d_in[0];
    const int*   mask   = (const int*)d_in[1];
    const float* We     = (const float*)d_in[2];
    const float* be     = (const float*)d_in[3];
    const float* Wa     = (const float*)d_in[4];
    const float* ba     = (const float*)d_in[5];
    const float* Wr     = (const float*)d_in[6];
    const float* br     = (const float*)d_in[7];
    const float* Wz     = (const float*)d_in[8];
    const float* bz     = (const float*)d_in[9];
    const float* Wh     = (const float*)d_in[10];
    const float* bh     = (const float*)d_in[11];
    float* out = (float*)d_out;
    float* ws = (float*)d_ws;

    const size_t need = (2*MSG_SZ + 3*COL_SZ + PROP_SZ) * sizeof(float);  // ~11.8 MB
    if (ws_size >= need) {
        float* msg0  = ws;
        float* msg1  = msg0 + MSG_SZ;
        float* colv0 = msg1 + MSG_SZ;
        float* colv1 = colv0 + COL_SZ;
        float* rowv  = colv1 + COL_SZ;
        float* prop  = rowv + COL_SZ;

        // prologue: PhaseA(0) only, prop source = inputs, writes msg(0)->buf0
        k_iter<0,1><<<BB*NN/4, 256, 0, stream>>>(
            inputs, prop, msg1, msg0, colv1, colv0, rowv, rowv, mask,
            We, be, Wa, ba, Wr, br, Wz, bz, Wh, bh, out);

        for (int t = 0; t < TT; ++t) {
            const float* msgR  = (t & 1) ? msg1 : msg0;
            float*       msgW  = (t & 1) ? msg0 : msg1;
            const float* colvR = (t & 1) ? colv1 : colv0;
            float*       colvW = (t & 1) ? colv0 : colv1;
            const float* propR = (t == 0) ? inputs : prop;
            float* out_t = out + (size_t)t * BB * NN * NE;
            if (t < TT - 1)
                k_iter<1,1><<<BB*NN/4, 256, 0, stream>>>(
                    propR, prop, msgR, msgW, colvR, colvW, rowv, rowv, mask,
                    We, be, Wa, ba, Wr, br, Wz, bz, Wh, bh, out_t);
            else
                k_iter<1,0><<<BB*NN/4, 256, 0, stream>>>(
                    propR, prop, msgR, msgW, colvR, colvW, rowv, rowv, mask,
                    We, be, Wa, ba, Wr, br, Wz, bz, Wh, bh, out_t);
        }
        return;
    }

    // ---- fallback: round-2 two-kernel path ----
    float* prop = ws;
    float* msg  = prop + PROP_SZ;
    float* rowv = msg + MSG_SZ;
    float* colv = rowv + COL_SZ;

    hipMemcpyAsync(prop, inputs, PROP_SZ * sizeof(float),
                   hipMemcpyDeviceToDevice, stream);

    for (int t = 0; t < TT; ++t) {
        k_msg<<<BB*NN/4, EE*DD, 0, stream>>>(prop, We, be, Wa, msg, rowv, colv);
        float* out_t = out + (size_t)t * BB * NN * NE;
        // reuse k_iter<1,0> as the B-only kernel (reads prop from global, no A)
        k_iter<1,0><<<BB*NN/4, 256, 0, stream>>>(
            prop, prop, msg, msg, colv, colv, rowv, rowv, mask,
            We, be, Wa, ba, Wr, br, Wz, bz, Wh, bh, out_t);
    }
}

// Round 7
// 305.923 us; speedup vs baseline: 1.2386x; 1.2386x over previous
//
#include <hip/hip_runtime.h>
#include <math.h>

#define BB 32
#define NN 128
#define DD 64
#define EE 5
#define TT 6          // 1+T iterations
#define NE (NN*EE)    // 640
#define MSG_SZ ((size_t)BB*NN*EE*DD)   // 1310720
#define COL_SZ ((size_t)BB*NN*EE)      // 20480
#define PROP_SZ ((size_t)BB*NN*DD)     // 262144

__device__ __forceinline__ float fsig(float x) {
    float t = __expf(-x);
    return __fdividef(1.f, 1.f + t);
}
__device__ __forceinline__ float ftanh_(float x) {
    float xc = fminf(fmaxf(x, -15.f), 15.f);
    float t = __expf(-2.f * xc);
    return 1.f - __fdividef(2.f * t, 1.f + t);
}

// ===================== per-iteration kernel (2 rows/block) =====================
// k_iter<DO_B,DO_A>: PhaseB(t) (scores->out, merged, GRU) then PhaseA(t+1)
// (msg/rowv/colv for own rows from freshly updated LDS prop).
// Block owns 2 (b,i) rows; 256 threads (4 waves); grid = B*N/2 = 2048.
// blockIdx swizzled so all blocks of batch b land on XCD b%8 (L2 locality).
template<int DO_B, int DO_A>
__global__ void __launch_bounds__(256) k_iter(
    const float* __restrict__ propR, float* __restrict__ propW,
    const float* __restrict__ msgR, float* __restrict__ msgW,
    const float* __restrict__ colvR, float* __restrict__ colvW,
    const float* __restrict__ rowvR, float* __restrict__ rowvW,
    const int* __restrict__ mask,
    const float* __restrict__ We, const float* __restrict__ be,
    const float* __restrict__ Wa, const float* __restrict__ ba,
    const float* __restrict__ Wr, const float* __restrict__ br,
    const float* __restrict__ Wz, const float* __restrict__ bz,
    const float* __restrict__ Wh, const float* __restrict__ bh,
    float* __restrict__ out_t)
{
    // XCD-locality swizzle: hw XCD = bid%8; batch b served by XCD b%8.
    const int bid = blockIdx.x;
    const int x = bid & 7;              // this block's XCD (assumed)
    const int s = bid >> 3;             // 0..255 within XCD
    const int b = x + 8 * (s >> 6);     // 4 batches per XCD
    const int it = s & 63;              // i-tile within batch
    const int bi0 = b * NN + it * 2;

    const int tid = threadIdx.x;
    const int g = tid >> 6;        // wave 0..3
    const int f = tid & 63;        // lane
    const int d = f;

    __shared__ float s_pt[DD][2];         // prop transposed [d][q]
    __shared__ float s_mt[DD][2];         // merged transposed
    __shared__ float s_rpt[DD][2];        // r*prop
    __shared__ float s_sc[NE][2];         // scores [je][q]
    __shared__ float s_part[4][2][DD];
    __shared__ float s_part2[4][2][DD];
    __shared__ float s_rv[2][EE];         // row logits for own 2 rows

    if (tid < 2 * DD) s_pt[f][g] = propR[(bi0 + g) * DD + f];   // g = q here (0/1)
    if (DO_B && tid < 2 * EE) s_rv[tid / EE][tid % EE] = rowvR[bi0 * EE + tid];
    __syncthreads();

    if (DO_B) {
        // ---- scores -> out + LDS ----
        for (int je = tid; je < NE; je += 256) {
            const int j = je / EE, e = je - j * EE;
            const float cv = colvR[b * NE + je] + ba[e];
            #pragma unroll
            for (int qq = 0; qq < 2; ++qq) {
                float lg = s_rv[qq][e] + cv;
                float m = (float)mask[((size_t)(b * NN) + (it * 2) + qq) * NN + j];
                float sc = fsig(lg) * m;
                s_sc[je][qq] = sc;
                out_t[(size_t)(bi0 + qq) * NE + je] = sc;
            }
        }
        __syncthreads();

        // ---- merged partials: wave g covers je in [g*160, g*160+160) ----
        {
            const float* mb = msgR + (size_t)b * NE * DD;
            float a0 = 0.f, a1 = 0.f;
            const int je0 = g * 160;
            #pragma unroll 8
            for (int je = je0; je < je0 + 160; ++je) {
                float m = mb[(size_t)je * DD + d];
                float2 sc = *(const float2*)&s_sc[je][0];
                a0 = fmaf(sc.x, m, a0); a1 = fmaf(sc.y, m, a1);
            }
            s_part[g][0][d] = a0; s_part[g][1][d] = a1;
        }
        __syncthreads();

        // ---- combine merged (threads tid<128: q = tid>>6, d) ----
        float p_reg = 0.f, z_reg = 0.f;
        const int q = g;    // valid for tid<128
        if (tid < 128) {
            float m_reg = s_part[0][q][d] + s_part[1][q][d]
                        + s_part[2][q][d] + s_part[3][q][d];
            p_reg = s_pt[d][q];
            s_mt[d][q] = m_reg;
        }
        __syncthreads();

        // ---- gates r,z: wave g covers a k-quarter; weights read once/block ----
        {
            const float* vsrc = (g & 2) ? &s_pt[0][0] : &s_mt[0][0];
            const int kbase = (g & 2) ? 64 : 0;
            const int k0 = (g & 1) * 32;
            float r0=0,r1=0, z0=0,z1=0;
            #pragma unroll 8
            for (int kk = 0; kk < 32; ++kk) {
                int k = k0 + kk;
                int kg = kbase + k;
                float wr = Wr[kg * DD + d];
                float wz = Wz[kg * DD + d];
                float2 v = *(const float2*)&vsrc[k * 2];
                r0=fmaf(v.x,wr,r0); r1=fmaf(v.y,wr,r1);
                z0=fmaf(v.x,wz,z0); z1=fmaf(v.y,wz,z1);
            }
            s_part[g][0][d]=r0; s_part[g][1][d]=r1;
            s_part2[g][0][d]=z0; s_part2[g][1][d]=z1;
        }
        __syncthreads();

        if (tid < 128) {
            float ar = br[d] + s_part[0][q][d] + s_part[1][q][d] + s_part[2][q][d] + s_part[3][q][d];
            float az = bz[d] + s_part2[0][q][d] + s_part2[1][q][d] + s_part2[2][q][d] + s_part2[3][q][d];
            float r = fsig(ar);
            z_reg = fsig(az);
            s_rpt[d][q] = r * p_reg;
        }
        __syncthreads();

        // ---- gate h: same k-split over [merged | r*prop] ----
        {
            const float* vsrc = (g & 2) ? &s_rpt[0][0] : &s_mt[0][0];
            const int kbase = (g & 2) ? 64 : 0;
            const int k0 = (g & 1) * 32;
            float h0=0,h1=0;
            #pragma unroll 8
            for (int kk = 0; kk < 32; ++kk) {
                int k = k0 + kk;
                int kg = kbase + k;
                float wh = Wh[kg * DD + d];
                float2 v = *(const float2*)&vsrc[k * 2];
                h0=fmaf(v.x,wh,h0); h1=fmaf(v.y,wh,h1);
            }
            s_part[g][0][d]=h0; s_part[g][1][d]=h1;
        }
        __syncthreads();

        if (tid < 128) {
            float ah = bh[d] + s_part[0][q][d] + s_part[1][q][d] + s_part[2][q][d] + s_part[3][q][d];
            float hh = ftanh_(ah);
            float pn = (1.f - z_reg) * p_reg + z_reg * hh;
            s_pt[d][q] = pn;                       // for PhaseA below
            propW[(bi0 + q) * DD + d] = pn;        // for next launch's PhaseB
        }
        __syncthreads();
    }

    if (DO_A) {
        // ---- A1: wave g does expert e=g fully (2 rows) + a 16-k slice of e=4 ----
        {
            const int e = g;
            const float* w = We + e * DD * DD + f;
            const float bias = be[e * DD + f];
            float a0 = bias, a1 = bias;
            #pragma unroll 8
            for (int k = 0; k < DD; ++k) {
                float wv = w[k * DD];
                float2 p = *(const float2*)&s_pt[k][0];
                a0 = fmaf(p.x, wv, a0); a1 = fmaf(p.y, wv, a1);
            }
            msgW[((size_t)(bi0+0)*EE + e)*DD + f] = a0;
            msgW[((size_t)(bi0+1)*EE + e)*DD + f] = a1;

            const float war = Wa[e*2*DD + f], wac = Wa[e*2*DD + DD + f];
            float r0=a0*war, r1=a1*war;
            float c0=a0*wac, c1=a1*wac;
            #pragma unroll
            for (int off = 32; off; off >>= 1) {
                r0 += __shfl_xor(r0,off); r1 += __shfl_xor(r1,off);
                c0 += __shfl_xor(c0,off); c1 += __shfl_xor(c1,off);
            }
            if (f == 0) {
                rowvW[(bi0+0)*EE+e]=r0; rowvW[(bi0+1)*EE+e]=r1;
                colvW[(bi0+0)*EE+e]=c0; colvW[(bi0+1)*EE+e]=c1;
            }

            // e=4 partial over k in [g*16, g*16+16)
            const float* w4 = We + 4 * DD * DD + f;
            float pa0 = 0.f, pa1 = 0.f;
            const int kk0 = g * 16;
            #pragma unroll 8
            for (int k = kk0; k < kk0 + 16; ++k) {
                float wv = w4[k * DD];
                float2 p = *(const float2*)&s_pt[k][0];
                pa0 = fmaf(p.x, wv, pa0); pa1 = fmaf(p.y, wv, pa1);
            }
            s_part[g][0][f] = pa0; s_part[g][1][f] = pa1;
        }
        __syncthreads();

        // ---- A2: combine e=4 (threads tid<128: q, f) ----
        if (tid < 128) {
            const int q = g;
            float m4 = be[4 * DD + f] + s_part[0][q][f] + s_part[1][q][f]
                                       + s_part[2][q][f] + s_part[3][q][f];
            msgW[((size_t)(bi0+q)*EE + 4)*DD + f] = m4;
            float pr = m4 * Wa[4*2*DD + f];
            float pc = m4 * Wa[4*2*DD + DD + f];
            #pragma unroll
            for (int off = 32; off; off >>= 1) {
                pr += __shfl_xor(pr, off);
                pc += __shfl_xor(pc, off);
            }
            if (f == 0) {
                rowvW[(bi0+q)*EE + 4] = pr;
                colvW[(bi0+q)*EE + 4] = pc;
            }
        }
    }
}

// ===================== fallback helper (round-2 proven) =====================
__global__ void __launch_bounds__(320) k_msg(
    const float* __restrict__ prop, const float* __restrict__ We,
    const float* __restrict__ be, const float* __restrict__ Wa,
    float* __restrict__ msg, float* __restrict__ rowv, float* __restrict__ colv)
{
    const int bn0 = blockIdx.x * 4;
    const int tid = threadIdx.x;
    const int e = tid >> 6, f = tid & 63;
    __shared__ float s_pt[DD][4];
    if (tid < 256) {
        int qq = tid >> 6, dd = tid & 63;
        s_pt[dd][qq] = prop[(bn0 + qq) * DD + dd];
    }
    __syncthreads();

    const float* w = We + e * DD * DD + f;
    const float bias = be[e * DD + f];
    float a0 = bias, a1 = bias, a2 = bias, a3 = bias;
    #pragma unroll 8
    for (int k = 0; k < DD; ++k) {
        float wv = w[k * DD];
        float4 p = *(const float4*)&s_pt[k][0];
        a0 = fmaf(p.x, wv, a0); a1 = fmaf(p.y, wv, a1);
        a2 = fmaf(p.z, wv, a2); a3 = fmaf(p.w, wv, a3);
    }
    msg[((size_t)(bn0+0)*EE + e)*DD + f] = a0;
    msg[((size_t)(bn0+1)*EE + e)*DD + f] = a1;
    msg[((size_t)(bn0+2)*EE + e)*DD + f] = a2;
    msg[((size_t)(bn0+3)*EE + e)*DD + f] = a3;

    const float war = Wa[e*2*DD + f], wac = Wa[e*2*DD + DD + f];
    float r0=a0*war, r1=a1*war, r2=a2*war, r3=a3*war;
    float c0=a0*wac, c1=a1*wac, c2=a2*wac, c3=a3*wac;
    #pragma unroll
    for (int off = 32; off; off >>= 1) {
        r0 += __shfl_xor(r0,off); r1 += __shfl_xor(r1,off);
        r2 += __shfl_xor(r2,off); r3 += __shfl_xor(r3,off);
        c0 += __shfl_xor(c0,off); c1 += __shfl_xor(c1,off);
        c2 += __shfl_xor(c2,off); c3 += __shfl_xor(c3,off);
    }
    if (f == 0) {
        rowv[(bn0+0)*EE+e]=r0; rowv[(bn0+1)*EE+e]=r1;
        rowv[(bn0+2)*EE+e]=r2; rowv[(bn0+3)*EE+e]=r3;
        colv[(bn0+0)*EE+e]=c0; colv[(bn0+1)*EE+e]=c1;
        colv[(bn0+2)*EE+e]=c2; colv[(bn0+3)*EE+e]=c3;
    }
}

extern "C" void kernel_launch(void* const* d_in, const int* in_sizes, int n_in,
                              void* d_out, int out_size, void* d_ws, size_t ws_size,
                              hipStream_t stream)
{
    const float* inputs = (const float*)d_in[0];
    const int*   mask   = (const int*)d_in[1];
    const float* We     = (const float*)d_in[2];
    const float* be     = (const float*)d_in[3];
    const float* Wa     = (const float*)d_in[4];
    const float* ba     = (const float*)d_in[5];
    const float* Wr     = (const float*)d_in[6];
    const float* br     = (const float*)d_in[7];
    const float* Wz     = (const float*)d_in[8];
    const float* bz     = (const float*)d_in[9];
    const float* Wh     = (const float*)d_in[10];
    const float* bh     = (const float*)d_in[11];
    float* out = (float*)d_out;
    float* ws = (float*)d_ws;

    const size_t need = (2*MSG_SZ + 3*COL_SZ + PROP_SZ) * sizeof(float);  // ~11.8 MB
    if (ws_size >= need) {
        float* msg0  = ws;
        float* msg1  = msg0 + MSG_SZ;
        float* colv0 = msg1 + MSG_SZ;
        float* colv1 = colv0 + COL_SZ;
        float* rowv  = colv1 + COL_SZ;
        float* prop  = rowv + COL_SZ;

        // prologue: PhaseA(0) only, prop source = inputs, writes msg(0)->buf0
        k_iter<0,1><<<BB*NN/2, 256, 0, stream>>>(
            inputs, prop, msg1, msg0, colv1, colv0, rowv, rowv, mask,
            We, be, Wa, ba, Wr, br, Wz, bz, Wh, bh, out);

        for (int t = 0; t < TT; ++t) {
            const float* msgR  = (t & 1) ? msg1 : msg0;
            float*       msgW  = (t & 1) ? msg0 : msg1;
            const float* colvR = (t & 1) ? colv1 : colv0;
            float*       colvW = (t & 1) ? colv0 : colv1;
            const float* propR = (t == 0) ? inputs : prop;
            float* out_t = out + (size_t)t * BB * NN * NE;
            if (t < TT - 1)
                k_iter<1,1><<<BB*NN/2, 256, 0, stream>>>(
                    propR, prop, msgR, msgW, colvR, colvW, rowv, rowv, mask,
                    We, be, Wa, ba, Wr, br, Wz, bz, Wh, bh, out_t);
            else
                k_iter<1,0><<<BB*NN/2, 256, 0, stream>>>(
                    propR, prop, msgR, msgW, colvR, colvW, rowv, rowv, mask,
                    We, be, Wa, ba, Wr, br, Wz, bz, Wh, bh, out_t);
        }
        return;
    }

    // ---- fallback: two-kernel path ----
    float* prop = ws;
    float* msg  = prop + PROP_SZ;
    float* rowv = msg + MSG_SZ;
    float* colv = rowv + COL_SZ;

    hipMemcpyAsync(prop, inputs, PROP_SZ * sizeof(float),
                   hipMemcpyDeviceToDevice, stream);

    for (int t = 0; t < TT; ++t) {
        k_msg<<<BB*NN/4, EE*DD, 0, stream>>>(prop, We, be, Wa, msg, rowv, colv);
        float* out_t = out + (size_t)t * BB * NN * NE;
        k_iter<1,0><<<BB*NN/2, 256, 0, stream>>>(
            prop, prop, msg, msg, colv, colv, rowv, rowv, mask,
            We, be, Wa, ba, Wr, br, Wz, bz, Wh, bh, out_t);
    }
}